// Round 2
// baseline (141.388 us; speedup 1.0000x reference)
//
#include <hip/hip_runtime.h>

typedef float f4 __attribute__((ext_vector_type(4)));

constexpr int D  = 128;
constexpr int B  = 1024;
constexpr int S1 = 25;    // inner fanout (hop2 -> hop1)
constexpr int S2 = 10;    // outer fanout (hop1 -> hop0)

// ---------------------------------------------------------------------------
// Fused layer-0 kernel (reverted to all-thread-gather structure, finer tiles):
//   RPB=8 rows per block -> 1280 nh1 blocks + 128 nh0 blocks = 1408 blocks.
//   launch_bounds(256,4): VGPR<=128 -> 4 blocks/CU resident (16 waves/CU), all
//   gathering concurrently; gather is latency-bound so resident-wave count is
//   the controlling resource (round-1's 2-producer-wave pipeline regressed 2x).
// Gather: thread t -> chunk l = t&31 (16B), row r = t>>5 (one row per thread,
//   25 (or 10) independent f4 loads accumulated in registers).
// ---------------------------------------------------------------------------
constexpr int RPB = 8;

template <int NB>
__device__ __forceinline__ void gather_phase(
    const float* __restrict__ feat, const int* __restrict__ self_idx,
    const int* __restrict__ neigh_idx, int base,
    float (*lds_h)[D], float (*lds_m)[D])
{
    const int t = threadIdx.x;
    const int l = t & 31;        // 16B chunk within row
    const int r = t >> 5;        // row [0,8)

    const int* __restrict__ idx = neigh_idx + (long)(base + r) * NB;

    f4 acc = {0.f, 0.f, 0.f, 0.f};
    #pragma unroll
    for (int s = 0; s < NB; ++s)
        acc += *((const f4*)(feat + (long)idx[s] * D) + l);
    const f4 sv = *((const f4*)(feat + (long)self_idx[base + r] * D) + l);

    *(f4*)(&lds_m[r][l * 4]) = acc * (1.f / NB);
    *(f4*)(&lds_h[r][l * 4]) = sv;
}

__global__ __launch_bounds__(256, 4) void layer0_fused_kernel(
    const float* __restrict__ feat,
    const int* __restrict__ s0, const int* __restrict__ s1,
    const int* __restrict__ s2,
    const float* __restrict__ Ws0, const float* __restrict__ Wn0,
    float* __restrict__ nh1, float* __restrict__ nh0)
{
    __shared__ float lds_h[RPB][D];
    __shared__ float lds_m[RPB][D];
    const int NB1 = (B * S2) / RPB;   // 1280
    const int b = blockIdx.x;

    float* out;
    int base;
    if (b < NB1) {
        base = b * RPB;
        gather_phase<S1>(feat, s1, s2, base, lds_h, lds_m);
        out = nh1;
    } else {
        base = (b - NB1) * RPB;
        gather_phase<S2>(feat, s0, s1, base, lds_h, lds_m);
        out = nh0;
    }
    __syncthreads();

    // ---- matmul: d = tid&127 owns column d; rh = tid>>7 picks 4-row half ----
    const int tid = threadIdx.x;
    const int d   = tid & 127;
    const int rh  = tid >> 7;

    float acc[RPB / 2];
    #pragma unroll
    for (int r = 0; r < RPB / 2; ++r) acc[r] = 0.f;

    #pragma unroll 4
    for (int k4 = 0; k4 < D / 4; ++k4) {
        const int k = k4 * 4;
        const float ws0 = Ws0[(k + 0) * D + d];
        const float ws1 = Ws0[(k + 1) * D + d];
        const float ws2 = Ws0[(k + 2) * D + d];
        const float ws3 = Ws0[(k + 3) * D + d];
        const float wn0 = Wn0[(k + 0) * D + d];
        const float wn1 = Wn0[(k + 1) * D + d];
        const float wn2 = Wn0[(k + 2) * D + d];
        const float wn3 = Wn0[(k + 3) * D + d];
        #pragma unroll
        for (int r = 0; r < RPB / 2; ++r) {
            const int rr = rh * (RPB / 2) + r;
            const f4 hv = *(const f4*)(&lds_h[rr][k]);
            const f4 mv = *(const f4*)(&lds_m[rr][k]);
            acc[r] += hv.x * ws0 + hv.y * ws1 + hv.z * ws2 + hv.w * ws3
                    + mv.x * wn0 + mv.y * wn1 + mv.z * wn2 + mv.w * wn3;
        }
    }

    #pragma unroll
    for (int r = 0; r < RPB / 2; ++r)
        out[(long)(base + rh * (RPB / 2) + r) * D + d] = fmaxf(acc[r], 0.f);
}

// ---------------------------------------------------------------------------
// Layer 1: self = nh0 rows direct; mean over S2 contiguous nh1 rows; identity.
// ---------------------------------------------------------------------------
constexpr int RPB_L = 4;
__global__ __launch_bounds__(128) void layer1_kernel(
    const float* __restrict__ nh0, const float* __restrict__ nh1,
    const float* __restrict__ Ws1, const float* __restrict__ Wn1,
    float* __restrict__ out)
{
    __shared__ float lds_h[RPB_L][D];
    __shared__ float lds_m[RPB_L][D];
    const int tid  = threadIdx.x;
    const int base = blockIdx.x * RPB_L;

    #pragma unroll
    for (int r = 0; r < RPB_L; ++r) {
        const int row = base + r;
        lds_h[r][tid] = nh0[(long)row * D + tid];
        float s = 0.f;
        #pragma unroll
        for (int n = 0; n < S2; ++n)
            s += nh1[((long)row * S2 + n) * D + tid];
        lds_m[r][tid] = s * (1.f / S2);
    }
    __syncthreads();

    const int d = tid;
    float acc[RPB_L];
    #pragma unroll
    for (int r = 0; r < RPB_L; ++r) acc[r] = 0.f;

    #pragma unroll 4
    for (int k4 = 0; k4 < D / 4; ++k4) {
        const int k = k4 * 4;
        const float ws0 = Ws1[(k + 0) * D + d];
        const float ws1 = Ws1[(k + 1) * D + d];
        const float ws2 = Ws1[(k + 2) * D + d];
        const float ws3 = Ws1[(k + 3) * D + d];
        const float wn0 = Wn1[(k + 0) * D + d];
        const float wn1 = Wn1[(k + 1) * D + d];
        const float wn2 = Wn1[(k + 2) * D + d];
        const float wn3 = Wn1[(k + 3) * D + d];
        #pragma unroll
        for (int r = 0; r < RPB_L; ++r) {
            const f4 hv = *(const f4*)(&lds_h[r][k]);
            const f4 mv = *(const f4*)(&lds_m[r][k]);
            acc[r] += hv.x * ws0 + hv.y * ws1 + hv.z * ws2 + hv.w * ws3
                    + mv.x * wn0 + mv.y * wn1 + mv.z * wn2 + mv.w * wn3;
        }
    }

    #pragma unroll
    for (int r = 0; r < RPB_L; ++r)
        out[(long)(base + r) * D + d] = acc[r];
}

extern "C" void kernel_launch(void* const* d_in, const int* in_sizes, int n_in,
                              void* d_out, int out_size, void* d_ws, size_t ws_size,
                              hipStream_t stream)
{
    const float* feat = (const float*)d_in[0];
    const float* Ws0  = (const float*)d_in[1];
    const float* Wn0  = (const float*)d_in[2];
    const float* Ws1  = (const float*)d_in[3];
    const float* Wn1  = (const float*)d_in[4];
    const int*   s0   = (const int*)d_in[5];
    const int*   s1   = (const int*)d_in[6];
    const int*   s2   = (const int*)d_in[7];
    float* out = (float*)d_out;

    float* nh1 = (float*)d_ws;                   // [B*S2, D]
    float* nh0 = nh1 + (size_t)(B * S2) * D;     // [B, D]

    const int grid0 = (B * S2) / RPB + B / RPB;  // 1280 + 128 = 1408
    layer0_fused_kernel<<<grid0, 256, 0, stream>>>(feat, s0, s1, s2, Ws0, Wn0, nh1, nh0);
    layer1_kernel<<<B / RPB_L, 128, 0, stream>>>(nh0, nh1, Ws1, Wn1, out);
}

// Round 3
// 55.210 us; speedup vs baseline: 2.5609x; 2.5609x over previous
//
#include <hip/hip_runtime.h>

typedef float f4 __attribute__((ext_vector_type(4)));

constexpr int D  = 128;
constexpr int B  = 1024;
constexpr int S1 = 25;    // inner fanout (hop2 -> hop1)
constexpr int S2 = 10;    // outer fanout (hop1 -> hop0)

// ---------------------------------------------------------------------------
// Layer-0 via global_load_lds staging (no VGPR load destinations):
//   RPB=8 output rows per block; 1280 nh1 blocks + 128 nh0 blocks = 1408.
//   nh1 block: 2 rounds x (stage 100 neighbor rows -> LDS, reduce mean) +
//              8 self rows staged once (LDS rows 100-107); then 8-row matmul.
//   One global_load_lds (size=16) moves a 1KB row-pair: lanes 0-31 -> row 2p,
//   lanes 32-63 -> row 2p+1; LDS dest is wave-uniform base + lane*16 (linear).
//   ~14 instrs/wave all issued before any wait -> ~54KB in flight per block,
//   2 blocks/CU resident (58KB LDS) -> ~108KB/CU in flight: gather goes
//   BW-bound instead of VGPR-chunked latency-bound (R0..R2 failure mode).
// ---------------------------------------------------------------------------
constexpr int RPB   = 8;
constexpr int NROWS = 108;   // 100 neighbor rows (per round) + 8 self rows

#define GLD16(src, dst) __builtin_amdgcn_global_load_lds(                      \
    (const __attribute__((address_space(1))) void*)(src),                      \
    (__attribute__((address_space(3))) void*)(dst), 16, 0, 0)

__device__ __forceinline__ void load_pair(const float* feat, int gi, int lane,
                                          float* nbuf, int dst_pair)
{
    // per-lane global source (row gi, 16B chunk lane&31); wave-uniform LDS base
    const float* src = feat + (size_t)gi * D + (lane & 31) * 4;
    GLD16(src, nbuf + dst_pair * (2 * D));
}

__device__ __forceinline__ void reduce25(int t, const float* nbuf,
                                         float (*lds_m)[D], int r2)
{
    // wave r owns output r of this round; lane-halves split s = [0,13)/[13,25)
    const int c = t & 31;
    const int g = t >> 5;
    const int r = g >> 1;        // == wave id
    const int h = g & 1;
    f4 acc = {0.f, 0.f, 0.f, 0.f};
    #pragma unroll
    for (int k = 0; k < 13; ++k) {
        const int s = h * 13 + k;
        if (s < 25)
            acc += *(const f4*)(nbuf + (r * 25 + s) * D + c * 4);
    }
    acc.x += __shfl_xor(acc.x, 32);
    acc.y += __shfl_xor(acc.y, 32);
    acc.z += __shfl_xor(acc.z, 32);
    acc.w += __shfl_xor(acc.w, 32);
    if (h == 0)
        *(f4*)(&lds_m[r2 * 4 + r][c * 4]) = acc * (1.f / 25.f);
}

__device__ __forceinline__ void matmul_store(
    int t, const float* nbuf, const float (*lds_m)[D],
    const float* __restrict__ Ws, const float* __restrict__ Wn,
    float* __restrict__ outrows)
{
    const int d  = t & 127;
    const int rh = t >> 7;                     // 4-row half
    const float* hbase = nbuf + (100 + rh * 4) * D;
    float acc[4] = {0.f, 0.f, 0.f, 0.f};

    #pragma unroll 4
    for (int k4 = 0; k4 < D / 4; ++k4) {
        const int k = k4 * 4;
        const float ws0 = Ws[(k + 0) * D + d], ws1 = Ws[(k + 1) * D + d],
                    ws2 = Ws[(k + 2) * D + d], ws3 = Ws[(k + 3) * D + d];
        const float wn0 = Wn[(k + 0) * D + d], wn1 = Wn[(k + 1) * D + d],
                    wn2 = Wn[(k + 2) * D + d], wn3 = Wn[(k + 3) * D + d];
        #pragma unroll
        for (int r = 0; r < 4; ++r) {
            const f4 hv = *(const f4*)(hbase + r * D + k);
            const f4 mv = *(const f4*)(&lds_m[rh * 4 + r][k]);
            acc[r] += hv.x * ws0 + hv.y * ws1 + hv.z * ws2 + hv.w * ws3
                    + mv.x * wn0 + mv.y * wn1 + mv.z * wn2 + mv.w * wn3;
        }
    }
    #pragma unroll
    for (int r = 0; r < 4; ++r)
        outrows[(size_t)(rh * 4 + r) * D + d] = fmaxf(acc[r], 0.f);
}

__global__ __launch_bounds__(256, 2) void layer0_kernel(
    const float* __restrict__ feat,
    const int* __restrict__ s0, const int* __restrict__ s1,
    const int* __restrict__ s2,
    const float* __restrict__ Ws0, const float* __restrict__ Wn0,
    float* __restrict__ nh1, float* __restrict__ nh0)
{
    __shared__ float nbuf[NROWS * D];      // 54 KB
    __shared__ float lds_m[RPB][D];        // 4 KB

    const int NB1  = (B * S2) / RPB;       // 1280
    const int b    = blockIdx.x;
    const int t    = threadIdx.x;
    const int w    = t >> 6;
    const int lane = t & 63;
    const int half = lane >> 5;

    if (b < NB1) {
        const int base = b * RPB;
        const int* __restrict__ nidx = s2 + (size_t)base * S1;
        const int* __restrict__ sidx = s1 + base;

        // prefetch ALL pair indices for both rounds (no idx->load stalls later)
        int gi0[14], gi1[13];
        #pragma unroll
        for (int i = 0; i < 14; ++i) {
            const int p = w + i * 4;
            if (p < 54) {
                const int j = 2 * p + half;          // rows 0-99 neigh, 100-107 self
                gi0[i] = (j < 100) ? nidx[j] : sidx[j - 100];
            }
        }
        #pragma unroll
        for (int i = 0; i < 13; ++i) {
            const int p = w + i * 4;
            if (p < 50) gi1[i] = nidx[100 + 2 * p + half];
        }

        // round 0: outputs 0-3 neighbors (rows 0-99) + all 8 self (rows 100-107)
        #pragma unroll
        for (int i = 0; i < 14; ++i) {
            const int p = w + i * 4;
            if (p < 54) load_pair(feat, gi0[i], lane, nbuf, p);
        }
        __syncthreads();
        reduce25(t, nbuf, lds_m, 0);
        __syncthreads();

        // round 1: outputs 4-7 neighbors (rows 0-99 restaged)
        #pragma unroll
        for (int i = 0; i < 13; ++i) {
            const int p = w + i * 4;
            if (p < 50) load_pair(feat, gi1[i], lane, nbuf, p);
        }
        __syncthreads();
        reduce25(t, nbuf, lds_m, 1);
        __syncthreads();

        matmul_store(t, nbuf, lds_m, Ws0, Wn0, nh1 + (size_t)base * D);
    } else {
        const int base = (b - NB1) * RPB;
        const int* __restrict__ nidx = s1 + (size_t)base * S2;
        const int* __restrict__ sidx = s0 + base;

        // single round: 80 neighbor rows (0-79) + 8 self rows at 100-107
        int gi[11];
        #pragma unroll
        for (int i = 0; i < 11; ++i) {
            const int p = w + i * 4;               // p in [0,44) always
            const int j = 2 * p + half;
            gi[i] = (j < 80) ? nidx[j] : sidx[j - 80];
        }
        #pragma unroll
        for (int i = 0; i < 11; ++i) {
            const int p    = w + i * 4;
            const int dstp = (p < 40) ? p : (50 + (p - 40));   // self -> rows 100+
            load_pair(feat, gi[i], lane, nbuf, dstp);
        }
        __syncthreads();
        {   // reduce: 32-lane group g owns output g (10 rows, no shfl needed)
            const int o = t >> 5, c = t & 31;
            f4 acc = {0.f, 0.f, 0.f, 0.f};
            #pragma unroll
            for (int s = 0; s < S2; ++s)
                acc += *(const f4*)(nbuf + (o * S2 + s) * D + c * 4);
            *(f4*)(&lds_m[o][c * 4]) = acc * (1.f / S2);
        }
        __syncthreads();
        matmul_store(t, nbuf, lds_m, Ws0, Wn0, nh0 + (size_t)base * D);
    }
}

// ---------------------------------------------------------------------------
// Layer 1: self = nh0 rows direct; mean over S2 contiguous nh1 rows; identity.
// ---------------------------------------------------------------------------
constexpr int RPB_L = 4;
__global__ __launch_bounds__(128) void layer1_kernel(
    const float* __restrict__ nh0, const float* __restrict__ nh1,
    const float* __restrict__ Ws1, const float* __restrict__ Wn1,
    float* __restrict__ out)
{
    __shared__ float lds_h[RPB_L][D];
    __shared__ float lds_m[RPB_L][D];
    const int tid  = threadIdx.x;
    const int base = blockIdx.x * RPB_L;

    #pragma unroll
    for (int r = 0; r < RPB_L; ++r) {
        const int row = base + r;
        lds_h[r][tid] = nh0[(long)row * D + tid];
        float s = 0.f;
        #pragma unroll
        for (int n = 0; n < S2; ++n)
            s += nh1[((long)row * S2 + n) * D + tid];
        lds_m[r][tid] = s * (1.f / S2);
    }
    __syncthreads();

    const int d = tid;
    float acc[RPB_L];
    #pragma unroll
    for (int r = 0; r < RPB_L; ++r) acc[r] = 0.f;

    #pragma unroll 4
    for (int k4 = 0; k4 < D / 4; ++k4) {
        const int k = k4 * 4;
        const float ws0 = Ws1[(k + 0) * D + d];
        const float ws1 = Ws1[(k + 1) * D + d];
        const float ws2 = Ws1[(k + 2) * D + d];
        const float ws3 = Ws1[(k + 3) * D + d];
        const float wn0 = Wn1[(k + 0) * D + d];
        const float wn1 = Wn1[(k + 1) * D + d];
        const float wn2 = Wn1[(k + 2) * D + d];
        const float wn3 = Wn1[(k + 3) * D + d];
        #pragma unroll
        for (int r = 0; r < RPB_L; ++r) {
            const f4 hv = *(const f4*)(&lds_h[r][k]);
            const f4 mv = *(const f4*)(&lds_m[r][k]);
            acc[r] += hv.x * ws0 + hv.y * ws1 + hv.z * ws2 + hv.w * ws3
                    + mv.x * wn0 + mv.y * wn1 + mv.z * wn2 + mv.w * wn3;
        }
    }

    #pragma unroll
    for (int r = 0; r < RPB_L; ++r)
        out[(long)(base + r) * D + d] = acc[r];
}

extern "C" void kernel_launch(void* const* d_in, const int* in_sizes, int n_in,
                              void* d_out, int out_size, void* d_ws, size_t ws_size,
                              hipStream_t stream)
{
    const float* feat = (const float*)d_in[0];
    const float* Ws0  = (const float*)d_in[1];
    const float* Wn0  = (const float*)d_in[2];
    const float* Ws1  = (const float*)d_in[3];
    const float* Wn1  = (const float*)d_in[4];
    const int*   s0   = (const int*)d_in[5];
    const int*   s1   = (const int*)d_in[6];
    const int*   s2   = (const int*)d_in[7];
    float* out = (float*)d_out;

    float* nh1 = (float*)d_ws;                   // [B*S2, D]
    float* nh0 = nh1 + (size_t)(B * S2) * D;     // [B, D]

    const int grid0 = (B * S2) / RPB + B / RPB;  // 1280 + 128 = 1408
    layer0_kernel<<<grid0, 256, 0, stream>>>(feat, s0, s1, s2, Ws0, Wn0, nh1, nh0);
    layer1_kernel<<<B / RPB_L, 128, 0, stream>>>(nh0, nh1, Ws1, Wn1, out);
}